// Round 6
// baseline (422.020 us; speedup 1.0000x reference)
//
#include <hip/hip_runtime.h>
#include <hip/hip_bf16.h>

#define N_NODES 50000
#define N_EDGES 800000
#define DIN 256
#define HD 128   // H*D
#define NH 4
#define RB 16    // rows per GEMM block; 50000 = 3125 * 16 exactly
#define CAP 64   // max in-degree bucket capacity (Poisson(16): P(>64) ~ 1e-20)

// ---------------- GEMM: h = x @ W (fp32) + fused attention dots ----------------
// 16 rows per 128-thread block; thread = output column.
// x is wave-uniform per (r,k) -> scalar loads (s_load_dwordx4) on the scalar
// pipe; W is the only vector-memory operand; VALU runs pure FMA.
__global__ void gemm_kernel(const float* __restrict__ x,
                            const float* __restrict__ W,
                            const float* __restrict__ a_src,
                            const float* __restrict__ a_dst,
                            float* __restrict__ h,
                            float* __restrict__ ssrc,
                            float* __restrict__ sdst) {
  const int row0 = blockIdx.x * RB;
  const int tid  = threadIdx.x;
  const float* __restrict__ xrow = x + (size_t)row0 * DIN;

  float acc[RB];
#pragma unroll
  for (int r = 0; r < RB; r++) acc[r] = 0.f;

  for (int k4 = 0; k4 < DIN / 4; k4++) {
    const int k = k4 * 4;
    float w0 = W[(k + 0) * HD + tid];
    float w1 = W[(k + 1) * HD + tid];
    float w2 = W[(k + 2) * HD + tid];
    float w3 = W[(k + 3) * HD + tid];
#pragma unroll
    for (int r = 0; r < RB; r++) {
      // fully uniform address -> scalar load, broadcast via SGPR operand
      float4 xv = *(const float4*)(xrow + (size_t)r * DIN + k);
      acc[r] = fmaf(xv.x, w0, acc[r]);
      acc[r] = fmaf(xv.y, w1, acc[r]);
      acc[r] = fmaf(xv.z, w2, acc[r]);
      acc[r] = fmaf(xv.w, w3, acc[r]);
    }
  }

  const float av = a_src[tid];
  const float dv = a_dst[tid];
  const int hh = tid >> 5;   // head id (wave0: heads 0,1; wave1: heads 2,3)

#pragma unroll
  for (int r = 0; r < RB; r++) {
    int row = row0 + r;
    h[(size_t)row * HD + tid] = acc[r];
    float ps = acc[r] * av;
    float pd = acc[r] * dv;
    // reduce within each 32-lane head group (xor masks <32 stay in-group)
#pragma unroll
    for (int m = 16; m >= 1; m >>= 1) {
      ps += __shfl_xor(ps, m, 64);
      pd += __shfl_xor(pd, m, 64);
    }
    if ((tid & 31) == 0) {
      ssrc[row * NH + hh] = ps;
      sdst[row * NH + hh] = pd;
    }
  }
}

// ---------------- zero bucket cursors ----------------
__global__ void zero_kernel(int* __restrict__ cursor) {
  int i = blockIdx.x * 256 + threadIdx.x;
  if (i < N_NODES) cursor[i] = 0;
}

// ---------------- scatter edges into fixed-CAP dst buckets ----------------
// 8 B payload per edge: (src index, gate bits). No float atomics.
__global__ void scatter_kernel(const int2* __restrict__ adj,
                               const float* __restrict__ wts,
                               int* __restrict__ cursor,
                               int2* __restrict__ slots) {
  int e = blockIdx.x * 256 + threadIdx.x;
  if (e >= N_EDGES) return;
  int2 sd = adj[e];                      // x = src, y = dst
  if ((unsigned)sd.x >= (unsigned)N_NODES || (unsigned)sd.y >= (unsigned)N_NODES) return;
  float g = fmaxf(wts[e], 1e-6f);
  int pos = atomicAdd(&cursor[sd.y], 1);
  if (pos >= CAP) pos = CAP - 1;         // unreachable for this input; never corrupt
  slots[((size_t)sd.y << 6) + pos] = make_int2(sd.x, __float_as_int(g));
}

// ---------------- per-node: scores + softmax + aggregate + GELU ----------------
__global__ void node_kernel(const int* __restrict__ cursor,
                            const int2* __restrict__ slots,
                            const float4* __restrict__ ssrc4,
                            const float4* __restrict__ sdst4,
                            const float* __restrict__ h,
                            float* __restrict__ out) {
  const int n   = blockIdx.x;
  const int tid = threadIdx.x;
  const int hh  = tid >> 5;
  int deg = cursor[n];
  if (deg > CAP) deg = CAP;

  __shared__ float  sden[NH];
  __shared__ int    sidx[CAP];
  __shared__ float4 swv[CAP];
  if (tid < NH) sden[tid] = 0.f;
  __syncthreads();

  if (tid < deg) {
    int2 sl = slots[((size_t)n << 6) + tid];
    int s = sl.x;
    float g = __int_as_float(sl.y);
    float4 ss = ssrc4[s];        // 0.8 MB buffer: L2-resident gather
    float4 sd = sdst4[n];
    float4 ex;
    ex.x = g * expf(tanhf(ss.x + sd.x));
    ex.y = g * expf(tanhf(ss.y + sd.y));
    ex.z = g * expf(tanhf(ss.z + sd.z));
    ex.w = g * expf(tanhf(ss.w + sd.w));
    sidx[tid] = s;
    swv[tid] = make_float4(ex.x * g, ex.y * g, ex.z * g, ex.w * g);
    atomicAdd(&sden[0], ex.x);
    atomicAdd(&sden[1], ex.y);
    atomicAdd(&sden[2], ex.z);
    atomicAdd(&sden[3], ex.w);
  }
  __syncthreads();

  float dn  = sden[hh];
  float inv = (dn > 0.f) ? 1.f / dn : 0.f;

  float acc = 0.f;
  for (int j = 0; j < deg; j++) {
    float wj = ((const float*)&swv[j])[hh];                 // LDS broadcast
    acc = fmaf(wj, h[(size_t)sidx[j] * HD + tid], acc);     // coalesced 512B row
  }
  acc *= inv;   // softmax normalization hoisted out of the loop

  // exact GELU: x * 0.5 * (1 + erf(x/sqrt(2)))
  float gl = 0.5f * acc * (1.f + erff(acc * 0.70710678118654752f));
  out[(size_t)n * HD + tid] = gl;
}

extern "C" void kernel_launch(void* const* d_in, const int* in_sizes, int n_in,
                              void* d_out, int out_size, void* d_ws, size_t ws_size,
                              hipStream_t stream) {
  const float* x     = (const float*)d_in[0];
  const int2*  adj   = (const int2*)d_in[1];
  const float* wts   = (const float*)d_in[2];
  const float* W     = (const float*)d_in[3];
  const float* a_src = (const float*)d_in[4];
  const float* a_dst = (const float*)d_in[5];
  float* out = (float*)d_out;

  char* p = (char*)d_ws;
  auto carve = [&](size_t bytes) {
    char* q = p;
    p += (bytes + 255) & ~(size_t)255;
    return (void*)q;
  };
  // total ≈ 53 MB
  float* h      = (float*)carve((size_t)N_NODES * HD * sizeof(float));      // 25.6 MB
  float* ssrc   = (float*)carve((size_t)N_NODES * NH * sizeof(float));      // 0.8 MB
  float* sdst   = (float*)carve((size_t)N_NODES * NH * sizeof(float));      // 0.8 MB
  int2*  slots  = (int2*)carve((size_t)N_NODES * CAP * sizeof(int2));       // 25.6 MB
  int*   cursor = (int*)carve((size_t)N_NODES * sizeof(int));               // 0.2 MB

  zero_kernel<<<(N_NODES + 255) / 256, 256, 0, stream>>>(cursor);
  gemm_kernel<<<N_NODES / RB, 128, 0, stream>>>(x, W, a_src, a_dst, h, ssrc, sdst);
  scatter_kernel<<<(N_EDGES + 255) / 256, 256, 0, stream>>>(adj, wts, cursor, slots);
  node_kernel<<<N_NODES, 128, 0, stream>>>(cursor, slots, (const float4*)ssrc,
                                           (const float4*)sdst, h, out);
}

// Round 7
// 308.106 us; speedup vs baseline: 1.3697x; 1.3697x over previous
//
#include <hip/hip_runtime.h>
#include <hip/hip_bf16.h>

#define N_NODES 50000
#define N_EDGES 800000
#define DIN 256
#define HD 128   // H*D
#define NH 4
#define CAP 64   // max in-degree bucket capacity (Poisson(16): P(>64) ~ 1e-20)

#define ROWS 32      // rows per GEMM block
#define PAD_K 260    // LDS row stride (floats): 16B-aligned, breaks pow2 patterns

// ---------------- GEMM: h = x @ W (fp32) + fused attention dots ----------------
// 256 threads, tile 32 rows x 128 cols, thread = 4 rows x 4 cols.
// x staged in LDS (33.3 KB), read as ds_read_b128 along k (broadcast across
// the 32 lanes of each row-group). W via float4 from L2. 64 FMA per 4-k step.
__global__ __launch_bounds__(256, 2) void gemm_kernel(
    const float* __restrict__ x,
    const float* __restrict__ W,
    const float* __restrict__ a_src,
    const float* __restrict__ a_dst,
    float* __restrict__ h,
    float* __restrict__ ssrc,
    float* __restrict__ sdst) {
  __shared__ float xs[ROWS * PAD_K];   // 33,280 B
  const int tid  = threadIdx.x;
  const int row0 = blockIdx.x * ROWS;
  const int c    = tid & 31;           // col group: cols 4c..4c+3
  const int rg   = tid >> 5;           // row group: rows rg*4..rg*4+3

  // stage x[row0..row0+31][0..255] -> LDS (coalesced float4, conflict-free b128)
#pragma unroll
  for (int it = 0; it < 8; it++) {
    int i  = it * 256 + tid;           // 2048 float4 slots
    int r  = i >> 6;
    int kq = i & 63;
    float4 v = make_float4(0.f, 0.f, 0.f, 0.f);
    int row = row0 + r;
    if (row < N_NODES) v = *(const float4*)(x + (size_t)row * DIN + 4 * kq);
    *(float4*)&xs[r * PAD_K + 4 * kq] = v;
  }
  __syncthreads();

  float acc[4][4];
#pragma unroll
  for (int rr = 0; rr < 4; rr++)
#pragma unroll
    for (int cj = 0; cj < 4; cj++) acc[rr][cj] = 0.f;

  for (int k4 = 0; k4 < DIN / 4; k4++) {
    const int k = 4 * k4;
    float wv[4][4];
    *(float4*)wv[0] = *(const float4*)&W[(k + 0) * HD + 4 * c];
    *(float4*)wv[1] = *(const float4*)&W[(k + 1) * HD + 4 * c];
    *(float4*)wv[2] = *(const float4*)&W[(k + 2) * HD + 4 * c];
    *(float4*)wv[3] = *(const float4*)&W[(k + 3) * HD + 4 * c];
#pragma unroll
    for (int rr = 0; rr < 4; rr++) {
      float xv[4];
      *(float4*)xv = *(const float4*)&xs[(rg * 4 + rr) * PAD_K + k];
#pragma unroll
      for (int j = 0; j < 4; j++)
#pragma unroll
        for (int cj = 0; cj < 4; cj++)
          acc[rr][cj] = fmaf(xv[j], wv[j][cj], acc[rr][cj]);
    }
  }

  // epilogue: store h rows + per-head dots (head = c>>3; 8 lanes per head)
  float a_s[4], a_d[4];
  *(float4*)a_s = *(const float4*)&a_src[4 * c];
  *(float4*)a_d = *(const float4*)&a_dst[4 * c];
  const int head = c >> 3;

#pragma unroll
  for (int rr = 0; rr < 4; rr++) {
    int row = row0 + rg * 4 + rr;
    if (row >= N_NODES) break;   // uniform within each 8-lane reduce group
    *(float4*)&h[(size_t)row * HD + 4 * c] = *(float4*)acc[rr];
    float ps = acc[rr][0] * a_s[0] + acc[rr][1] * a_s[1] +
               acc[rr][2] * a_s[2] + acc[rr][3] * a_s[3];
    float pd = acc[rr][0] * a_d[0] + acc[rr][1] * a_d[1] +
               acc[rr][2] * a_d[2] + acc[rr][3] * a_d[3];
#pragma unroll
    for (int m = 4; m >= 1; m >>= 1) {   // reduce over the 8 lanes of this head
      ps += __shfl_xor(ps, m, 64);
      pd += __shfl_xor(pd, m, 64);
    }
    if ((c & 7) == 0) {
      ssrc[row * NH + head] = ps;
      sdst[row * NH + head] = pd;
    }
  }
}

// ---------------- zero bucket cursors ----------------
__global__ void zero_kernel(int* __restrict__ cursor) {
  int i = blockIdx.x * 256 + threadIdx.x;
  if (i < N_NODES) cursor[i] = 0;
}

// ---------------- scatter edges into fixed-CAP dst buckets ----------------
// 8 B payload per edge: (src index, gate bits). No float atomics.
__global__ void scatter_kernel(const int2* __restrict__ adj,
                               const float* __restrict__ wts,
                               int* __restrict__ cursor,
                               int2* __restrict__ slots) {
  int e = blockIdx.x * 256 + threadIdx.x;
  if (e >= N_EDGES) return;
  int2 sd = adj[e];                      // x = src, y = dst
  if ((unsigned)sd.x >= (unsigned)N_NODES || (unsigned)sd.y >= (unsigned)N_NODES) return;
  float g = fmaxf(wts[e], 1e-6f);
  int pos = atomicAdd(&cursor[sd.y], 1);
  if (pos >= CAP) pos = CAP - 1;         // unreachable for this input; never corrupt
  slots[((size_t)sd.y << 6) + pos] = make_int2(sd.x, __float_as_int(g));
}

// ---------------- per-node: scores + softmax + aggregate + GELU ----------------
__global__ void node_kernel(const int* __restrict__ cursor,
                            const int2* __restrict__ slots,
                            const float4* __restrict__ ssrc4,
                            const float4* __restrict__ sdst4,
                            const float* __restrict__ h,
                            float* __restrict__ out) {
  const int n   = blockIdx.x;
  const int tid = threadIdx.x;
  const int hh  = tid >> 5;
  int deg = cursor[n];
  if (deg > CAP) deg = CAP;

  __shared__ float  sden[NH];
  __shared__ int    sidx[CAP];
  __shared__ float4 swv[CAP];
  if (tid < NH) sden[tid] = 0.f;
  __syncthreads();

  if (tid < deg) {
    int2 sl = slots[((size_t)n << 6) + tid];
    int s = sl.x;
    float g = __int_as_float(sl.y);
    float4 ss = ssrc4[s];        // 0.8 MB buffer: L2-resident gather
    float4 sd = sdst4[n];
    float4 ex;
    ex.x = g * expf(tanhf(ss.x + sd.x));
    ex.y = g * expf(tanhf(ss.y + sd.y));
    ex.z = g * expf(tanhf(ss.z + sd.z));
    ex.w = g * expf(tanhf(ss.w + sd.w));
    sidx[tid] = s;
    swv[tid] = make_float4(ex.x * g, ex.y * g, ex.z * g, ex.w * g);
    atomicAdd(&sden[0], ex.x);
    atomicAdd(&sden[1], ex.y);
    atomicAdd(&sden[2], ex.z);
    atomicAdd(&sden[3], ex.w);
  }
  __syncthreads();

  float dn  = sden[hh];
  float inv = (dn > 0.f) ? 1.f / dn : 0.f;

  float acc = 0.f;
  for (int j = 0; j < deg; j++) {
    float wj = ((const float*)&swv[j])[hh];                 // LDS broadcast
    acc = fmaf(wj, h[(size_t)sidx[j] * HD + tid], acc);     // coalesced 512B row
  }
  acc *= inv;   // softmax normalization hoisted out of the loop

  // exact GELU: x * 0.5 * (1 + erf(x/sqrt(2)))
  float gl = 0.5f * acc * (1.f + erff(acc * 0.70710678118654752f));
  out[(size_t)n * HD + tid] = gl;
}

extern "C" void kernel_launch(void* const* d_in, const int* in_sizes, int n_in,
                              void* d_out, int out_size, void* d_ws, size_t ws_size,
                              hipStream_t stream) {
  const float* x     = (const float*)d_in[0];
  const int2*  adj   = (const int2*)d_in[1];
  const float* wts   = (const float*)d_in[2];
  const float* W     = (const float*)d_in[3];
  const float* a_src = (const float*)d_in[4];
  const float* a_dst = (const float*)d_in[5];
  float* out = (float*)d_out;

  char* p = (char*)d_ws;
  auto carve = [&](size_t bytes) {
    char* q = p;
    p += (bytes + 255) & ~(size_t)255;
    return (void*)q;
  };
  // total ≈ 53 MB
  float* h      = (float*)carve((size_t)N_NODES * HD * sizeof(float));      // 25.6 MB
  float* ssrc   = (float*)carve((size_t)N_NODES * NH * sizeof(float));      // 0.8 MB
  float* sdst   = (float*)carve((size_t)N_NODES * NH * sizeof(float));      // 0.8 MB
  int2*  slots  = (int2*)carve((size_t)N_NODES * CAP * sizeof(int2));       // 25.6 MB
  int*   cursor = (int*)carve((size_t)N_NODES * sizeof(int));               // 0.2 MB

  zero_kernel<<<(N_NODES + 255) / 256, 256, 0, stream>>>(cursor);
  gemm_kernel<<<(N_NODES + ROWS - 1) / ROWS, 256, 0, stream>>>(x, W, a_src, a_dst, h, ssrc, sdst);
  scatter_kernel<<<(N_EDGES + 255) / 256, 256, 0, stream>>>(adj, wts, cursor, slots);
  node_kernel<<<N_NODES, 128, 0, stream>>>(cursor, slots, (const float4*)ssrc,
                                           (const float4*)sdst, h, out);
}

// Round 8
// 248.204 us; speedup vs baseline: 1.7003x; 1.2413x over previous
//
#include <hip/hip_runtime.h>
#include <hip/hip_bf16.h>

#define N_NODES 50000
#define N_EDGES 800000
#define DIN 256
#define HD 128   // H*D
#define NH 4
#define CAP 64   // max in-degree bucket capacity (Poisson(16): P(>64) ~ 1e-20)

#define ROWS 32      // rows per GEMM block
#define PAD_K 260    // LDS row stride (floats): 16B-aligned, breaks pow2 patterns

static __device__ __forceinline__ unsigned short f2bu(float v) {
  __hip_bfloat16 b = __float2bfloat16(v);
  union { __hip_bfloat16 b; unsigned short u; } c; c.b = b; return c.u;
}

// ---------------- GEMM: h = x @ W (fp32 math, bf16 h out) + fused dots -------
// 256 threads, tile 32 rows x 128 cols, thread = 4 rows x 4 cols.
// x staged in LDS, ds_read_b128 along k; W via float4 from L2. 64 FMA / 4-k.
__global__ __launch_bounds__(256, 2) void gemm_kernel(
    const float* __restrict__ x,
    const float* __restrict__ W,
    const float* __restrict__ a_src,
    const float* __restrict__ a_dst,
    unsigned short* __restrict__ hbf,   // bf16 bits, [N_NODES][HD]
    float* __restrict__ ssrc,
    float* __restrict__ sdst) {
  __shared__ float xs[ROWS * PAD_K];   // 33,280 B
  const int tid  = threadIdx.x;
  const int row0 = blockIdx.x * ROWS;
  const int c    = tid & 31;           // col group: cols 4c..4c+3
  const int rg   = tid >> 5;           // row group: rows rg*4..rg*4+3

  // stage x[row0..row0+31][0..255] -> LDS (coalesced float4)
#pragma unroll
  for (int it = 0; it < 8; it++) {
    int i  = it * 256 + tid;           // 2048 float4 slots
    int r  = i >> 6;
    int kq = i & 63;
    float4 v = make_float4(0.f, 0.f, 0.f, 0.f);
    int row = row0 + r;
    if (row < N_NODES) v = *(const float4*)(x + (size_t)row * DIN + 4 * kq);
    *(float4*)&xs[r * PAD_K + 4 * kq] = v;
  }
  __syncthreads();

  float acc[4][4];
#pragma unroll
  for (int rr = 0; rr < 4; rr++)
#pragma unroll
    for (int cj = 0; cj < 4; cj++) acc[rr][cj] = 0.f;

  for (int k4 = 0; k4 < DIN / 4; k4++) {
    const int k = 4 * k4;
    float wv[4][4];
    *(float4*)wv[0] = *(const float4*)&W[(k + 0) * HD + 4 * c];
    *(float4*)wv[1] = *(const float4*)&W[(k + 1) * HD + 4 * c];
    *(float4*)wv[2] = *(const float4*)&W[(k + 2) * HD + 4 * c];
    *(float4*)wv[3] = *(const float4*)&W[(k + 3) * HD + 4 * c];
#pragma unroll
    for (int rr = 0; rr < 4; rr++) {
      float xv[4];
      *(float4*)xv = *(const float4*)&xs[(rg * 4 + rr) * PAD_K + k];
#pragma unroll
      for (int j = 0; j < 4; j++)
#pragma unroll
        for (int cj = 0; cj < 4; cj++)
          acc[rr][cj] = fmaf(xv[j], wv[j][cj], acc[rr][cj]);
    }
  }

  // epilogue: bf16 h store + per-head dots from fp32 accs (head = c>>3)
  float a_s[4], a_d[4];
  *(float4*)a_s = *(const float4*)&a_src[4 * c];
  *(float4*)a_d = *(const float4*)&a_dst[4 * c];
  const int head = c >> 3;

#pragma unroll
  for (int rr = 0; rr < 4; rr++) {
    int row = row0 + rg * 4 + rr;
    if (row >= N_NODES) break;   // uniform within each 8-lane reduce group
    ushort4 hp;
    hp.x = f2bu(acc[rr][0]);
    hp.y = f2bu(acc[rr][1]);
    hp.z = f2bu(acc[rr][2]);
    hp.w = f2bu(acc[rr][3]);
    *(ushort4*)&hbf[(size_t)row * HD + 4 * c] = hp;
    float ps = acc[rr][0] * a_s[0] + acc[rr][1] * a_s[1] +
               acc[rr][2] * a_s[2] + acc[rr][3] * a_s[3];
    float pd = acc[rr][0] * a_d[0] + acc[rr][1] * a_d[1] +
               acc[rr][2] * a_d[2] + acc[rr][3] * a_d[3];
#pragma unroll
    for (int m = 4; m >= 1; m >>= 1) {   // reduce over the 8 lanes of this head
      ps += __shfl_xor(ps, m, 64);
      pd += __shfl_xor(pd, m, 64);
    }
    if ((c & 7) == 0) {
      ssrc[row * NH + head] = ps;
      sdst[row * NH + head] = pd;
    }
  }
}

// ---------------- zero bucket cursors ----------------
__global__ void zero_kernel(int* __restrict__ cursor) {
  int i = blockIdx.x * 256 + threadIdx.x;
  if (i < N_NODES) cursor[i] = 0;
}

// ---------------- scatter edges into fixed-CAP dst buckets ----------------
__global__ void scatter_kernel(const int2* __restrict__ adj,
                               const float* __restrict__ wts,
                               int* __restrict__ cursor,
                               int2* __restrict__ slots) {
  int e = blockIdx.x * 256 + threadIdx.x;
  if (e >= N_EDGES) return;
  int2 sd = adj[e];                      // x = src, y = dst
  if ((unsigned)sd.x >= (unsigned)N_NODES || (unsigned)sd.y >= (unsigned)N_NODES) return;
  float g = fmaxf(wts[e], 1e-6f);
  int pos = atomicAdd(&cursor[sd.y], 1);
  if (pos >= CAP) pos = CAP - 1;         // unreachable for this input; never corrupt
  slots[((size_t)sd.y << 6) + pos] = make_int2(sd.x, __float_as_int(g));
}

// ---------------- per-node: scores + softmax + aggregate + GELU --------------
// 128 threads = 2 waves; wave w handles node 2*blockIdx.x + w.
// Lane l covers cols {2l, 2l+1}: one packed bf16-pair (4 B) load per gather,
// so a wave pulls a whole 256 B h-row with one coalesced instruction.
__global__ void node_kernel(const int* __restrict__ cursor,
                            const int2* __restrict__ slots,
                            const float4* __restrict__ ssrc4,
                            const float4* __restrict__ sdst4,
                            const unsigned int* __restrict__ hbf32, // bf16 pairs
                            float* __restrict__ out) {
  const int tid  = threadIdx.x;
  const int wid  = tid >> 6;           // 0/1: which node
  const int lane = tid & 63;
  const int n    = blockIdx.x * 2 + wid;
  const int hh   = lane >> 4;          // head of cols 2l,2l+1 (= (2l)>>5)

  int deg = cursor[n];
  if (deg > CAP) deg = CAP;

  __shared__ float  sden[2][NH];
  __shared__ int    sidx[2][CAP];
  __shared__ float4 swv[2][CAP];
  if (lane < NH) sden[wid][lane] = 0.f;
  __syncthreads();

  if (lane < deg) {
    int2 sl = slots[((size_t)n << 6) + lane];
    int s = sl.x;
    float g = __int_as_float(sl.y);
    float4 ss = ssrc4[s];        // 0.8 MB buffer: L2-resident gather
    float4 sd = sdst4[n];
    float4 ex;
    ex.x = g * expf(tanhf(ss.x + sd.x));
    ex.y = g * expf(tanhf(ss.y + sd.y));
    ex.z = g * expf(tanhf(ss.z + sd.z));
    ex.w = g * expf(tanhf(ss.w + sd.w));
    sidx[wid][lane] = s;
    swv[wid][lane] = make_float4(ex.x * g, ex.y * g, ex.z * g, ex.w * g);
    atomicAdd(&sden[wid][0], ex.x);
    atomicAdd(&sden[wid][1], ex.y);
    atomicAdd(&sden[wid][2], ex.z);
    atomicAdd(&sden[wid][3], ex.w);
  }
  __syncthreads();

  float dn  = sden[wid][hh];
  float inv = (dn > 0.f) ? 1.f / dn : 0.f;

  float acc0 = 0.f, acc1 = 0.f;
  for (int j = 0; j < deg; j++) {
    float wj = ((const float*)&swv[wid][j])[hh];            // LDS broadcast
    unsigned int u = hbf32[(size_t)sidx[wid][j] * (HD / 2) + lane];
    acc0 = fmaf(wj, __uint_as_float(u << 16), acc0);        // col 2l
    acc1 = fmaf(wj, __uint_as_float(u & 0xffff0000u), acc1);// col 2l+1
  }
  acc0 *= inv;
  acc1 *= inv;

  // exact GELU: x * 0.5 * (1 + erf(x/sqrt(2)))
  float2 gl;
  gl.x = 0.5f * acc0 * (1.f + erff(acc0 * 0.70710678118654752f));
  gl.y = 0.5f * acc1 * (1.f + erff(acc1 * 0.70710678118654752f));
  *(float2*)&out[(size_t)n * HD + 2 * lane] = gl;
}

extern "C" void kernel_launch(void* const* d_in, const int* in_sizes, int n_in,
                              void* d_out, int out_size, void* d_ws, size_t ws_size,
                              hipStream_t stream) {
  const float* x     = (const float*)d_in[0];
  const int2*  adj   = (const int2*)d_in[1];
  const float* wts   = (const float*)d_in[2];
  const float* W     = (const float*)d_in[3];
  const float* a_src = (const float*)d_in[4];
  const float* a_dst = (const float*)d_in[5];
  float* out = (float*)d_out;

  char* p = (char*)d_ws;
  auto carve = [&](size_t bytes) {
    char* q = p;
    p += (bytes + 255) & ~(size_t)255;
    return (void*)q;
  };
  // total ≈ 41 MB
  unsigned short* hbf = (unsigned short*)carve((size_t)N_NODES * HD * sizeof(unsigned short)); // 12.8 MB
  float* ssrc   = (float*)carve((size_t)N_NODES * NH * sizeof(float));      // 0.8 MB
  float* sdst   = (float*)carve((size_t)N_NODES * NH * sizeof(float));      // 0.8 MB
  int2*  slots  = (int2*)carve((size_t)N_NODES * CAP * sizeof(int2));       // 25.6 MB
  int*   cursor = (int*)carve((size_t)N_NODES * sizeof(int));               // 0.2 MB

  zero_kernel<<<(N_NODES + 255) / 256, 256, 0, stream>>>(cursor);
  gemm_kernel<<<(N_NODES + ROWS - 1) / ROWS, 256, 0, stream>>>(x, W, a_src, a_dst, hbf, ssrc, sdst);
  scatter_kernel<<<(N_EDGES + 255) / 256, 256, 0, stream>>>(adj, wts, cursor, slots);
  node_kernel<<<N_NODES / 2, 128, 0, stream>>>(cursor, slots, (const float4*)ssrc,
                                               (const float4*)sdst,
                                               (const unsigned int*)hbf, out);
}

// Round 9
// 247.850 us; speedup vs baseline: 1.7027x; 1.0014x over previous
//
#include <hip/hip_runtime.h>
#include <hip/hip_bf16.h>

#define N_NODES 50000
#define N_EDGES 800000
#define DIN 256
#define HD 128   // H*D
#define NH 4
#define CAP 64   // max in-degree bucket capacity (Poisson(16): P(>64) ~ 1e-20)

#define GROWS 64     // rows per GEMM block (4 waves x 16)
#define LDK 264      // LDS k-stride in bf16 elems (528 B: 16B-aligned, bank-even)

typedef __bf16 bf16x8 __attribute__((ext_vector_type(8)));
typedef float  f32x4  __attribute__((ext_vector_type(4)));

static __device__ __forceinline__ unsigned short f2bu(float v) {
  union { __hip_bfloat16 b; unsigned short u; } c;
  c.b = __float2bfloat16(v);
  return c.u;
}

// ---------------- W transpose+convert: Wt[c][k] = bf16(W[k][c]) ----------------
__global__ void wconv_kernel(const float* __restrict__ W,
                             unsigned short* __restrict__ Wt) {
  int i = blockIdx.x * 256 + threadIdx.x;   // 32768 elements
  int c = i >> 8, k = i & 255;
  Wt[c * 256 + k] = f2bu(W[k * HD + c]);
}

// ---------------- GEMM: h = x @ W via bf16 MFMA (fp32 accum) + fused dots ----
// 256 threads = 4 waves; wave w: rows row0+16w..+15, all 128 cols (8 tiles).
// A: x converted to bf16 in LDS; B: Wt (bf16, L1/L2-resident) direct global.
__global__ __launch_bounds__(256, 2) void gemm_kernel(
    const float* __restrict__ x,
    const unsigned short* __restrict__ Wt,   // bf16 bits [128][256]
    const float* __restrict__ a_src,
    const float* __restrict__ a_dst,
    unsigned short* __restrict__ hbf,        // bf16 bits [N_NODES][HD]
    float* __restrict__ ssrc,
    float* __restrict__ sdst) {
  __shared__ unsigned short xs[GROWS * LDK];   // 33,792 B
  const int tid  = threadIdx.x;
  const int row0 = blockIdx.x * GROWS;

  // stage + convert x[row0..row0+63][0..255] -> bf16 LDS
#pragma unroll
  for (int it = 0; it < 16; it++) {
    int i  = it * 256 + tid;     // 4096 float4 slots (64 rows x 64)
    int r  = i >> 6;
    int kq = i & 63;
    int row = row0 + r;
    float4 v = make_float4(0.f, 0.f, 0.f, 0.f);
    if (row < N_NODES) v = *(const float4*)(x + (size_t)row * DIN + 4 * kq);
    ushort4 b;
    b.x = f2bu(v.x); b.y = f2bu(v.y); b.z = f2bu(v.z); b.w = f2bu(v.w);
    *(ushort4*)&xs[r * LDK + 4 * kq] = b;    // ds_write_b64
  }
  __syncthreads();

  const int wid  = tid >> 6;      // wave id -> row stripe
  const int lane = tid & 63;
  const int m    = lane & 15;     // A row within tile / B col within tile
  const int q    = lane >> 4;     // quad

  f32x4 acc[8];
#pragma unroll
  for (int t = 0; t < 8; t++) acc[t] = (f32x4){0.f, 0.f, 0.f, 0.f};

  const unsigned short* xbase = &xs[(wid * 16 + m) * LDK];
#pragma unroll
  for (int s = 0; s < 8; s++) {             // k-step: k = 32s
    bf16x8 afrag = *(const bf16x8*)(xbase + 32 * s + 8 * q);   // A[m][32s+8q+j]
#pragma unroll
    for (int t = 0; t < 8; t++) {           // col tile: cols 16t..16t+15
      bf16x8 bfrag = *(const bf16x8*)(Wt + (size_t)(16 * t + m) * 256 + 32 * s + 8 * q);
      acc[t] = __builtin_amdgcn_mfma_f32_16x16x32_bf16(afrag, bfrag, acc[t], 0, 0, 0);
    }
  }

  // D layout: lane holds rows q*4+r (r=0..3), col m of each tile t.
  // h store (bf16) — quad lanes write 16 consecutive bf16 = 32 B segments.
#pragma unroll
  for (int t = 0; t < 8; t++) {
#pragma unroll
    for (int r = 0; r < 4; r++) {
      int row = row0 + wid * 16 + q * 4 + r;
      if (row < N_NODES) hbf[(size_t)row * HD + 16 * t + m] = f2bu(acc[t][r]);
    }
  }

  // head dots from fp32 accumulators; tile t belongs to head t>>1.
  float as[8], ad[8];
#pragma unroll
  for (int t = 0; t < 8; t++) {
    as[t] = a_src[16 * t + m];
    ad[t] = a_dst[16 * t + m];
  }
#pragma unroll
  for (int r = 0; r < 4; r++) {
    float ps[NH] = {0.f, 0.f, 0.f, 0.f};
    float pd[NH] = {0.f, 0.f, 0.f, 0.f};
#pragma unroll
    for (int t = 0; t < 8; t++) {
      ps[t >> 1] = fmaf(acc[t][r], as[t], ps[t >> 1]);
      pd[t >> 1] = fmaf(acc[t][r], ad[t], pd[t >> 1]);
    }
#pragma unroll
    for (int mm = 8; mm >= 1; mm >>= 1) {   // reduce across the 16 lanes of quad q
#pragma unroll
      for (int hh = 0; hh < NH; hh++) {
        ps[hh] += __shfl_xor(ps[hh], mm, 64);
        pd[hh] += __shfl_xor(pd[hh], mm, 64);
      }
    }
    int row = row0 + wid * 16 + q * 4 + r;
    if (m == 0 && row < N_NODES) {
#pragma unroll
      for (int hh = 0; hh < NH; hh++) {
        ssrc[row * NH + hh] = ps[hh];
        sdst[row * NH + hh] = pd[hh];
      }
    }
  }
}

// ---------------- zero bucket cursors ----------------
__global__ void zero_kernel(int* __restrict__ cursor) {
  int i = blockIdx.x * 256 + threadIdx.x;
  if (i < N_NODES) cursor[i] = 0;
}

// ---------------- scatter edges into fixed-CAP dst buckets ----------------
__global__ void scatter_kernel(const int2* __restrict__ adj,
                               const float* __restrict__ wts,
                               int* __restrict__ cursor,
                               int2* __restrict__ slots) {
  int e = blockIdx.x * 256 + threadIdx.x;
  if (e >= N_EDGES) return;
  int2 sd = adj[e];                      // x = src, y = dst
  if ((unsigned)sd.x >= (unsigned)N_NODES || (unsigned)sd.y >= (unsigned)N_NODES) return;
  float g = fmaxf(wts[e], 1e-6f);
  int pos = atomicAdd(&cursor[sd.y], 1);
  if (pos >= CAP) pos = CAP - 1;         // unreachable for this input; never corrupt
  slots[((size_t)sd.y << 6) + pos] = make_int2(sd.x, __float_as_int(g));
}

// ---------------- per-node: scores + softmax + aggregate + GELU --------------
// 128 threads = 2 waves; wave w handles node 2*blockIdx.x + w.
// Lane l covers cols {2l, 2l+1}: one packed bf16-pair (4 B) load per gather.
__global__ void node_kernel(const int* __restrict__ cursor,
                            const int2* __restrict__ slots,
                            const float4* __restrict__ ssrc4,
                            const float4* __restrict__ sdst4,
                            const unsigned int* __restrict__ hbf32, // bf16 pairs
                            float* __restrict__ out) {
  const int tid  = threadIdx.x;
  const int wid  = tid >> 6;           // 0/1: which node
  const int lane = tid & 63;
  const int n    = blockIdx.x * 2 + wid;
  const int hh   = lane >> 4;          // head of cols 2l,2l+1

  int deg = cursor[n];
  if (deg > CAP) deg = CAP;

  __shared__ float  sden[2][NH];
  __shared__ int    sidx[2][CAP];
  __shared__ float4 swv[2][CAP];
  if (lane < NH) sden[wid][lane] = 0.f;
  __syncthreads();

  if (lane < deg) {
    int2 sl = slots[((size_t)n << 6) + lane];
    int s = sl.x;
    float g = __int_as_float(sl.y);
    float4 ss = ssrc4[s];        // 0.8 MB buffer: L2-resident gather
    float4 sd = sdst4[n];
    float4 ex;
    ex.x = g * expf(tanhf(ss.x + sd.x));
    ex.y = g * expf(tanhf(ss.y + sd.y));
    ex.z = g * expf(tanhf(ss.z + sd.z));
    ex.w = g * expf(tanhf(ss.w + sd.w));
    sidx[wid][lane] = s;
    swv[wid][lane] = make_float4(ex.x * g, ex.y * g, ex.z * g, ex.w * g);
    atomicAdd(&sden[wid][0], ex.x);
    atomicAdd(&sden[wid][1], ex.y);
    atomicAdd(&sden[wid][2], ex.z);
    atomicAdd(&sden[wid][3], ex.w);
  }
  __syncthreads();

  float dn  = sden[wid][hh];
  float inv = (dn > 0.f) ? 1.f / dn : 0.f;

  float acc0 = 0.f, acc1 = 0.f;
  for (int j = 0; j < deg; j++) {
    float wj = ((const float*)&swv[wid][j])[hh];            // LDS broadcast
    unsigned int u = hbf32[(size_t)sidx[wid][j] * (HD / 2) + lane];
    acc0 = fmaf(wj, __uint_as_float(u << 16), acc0);        // col 2l
    acc1 = fmaf(wj, __uint_as_float(u & 0xffff0000u), acc1);// col 2l+1
  }
  acc0 *= inv;
  acc1 *= inv;

  // exact GELU: x * 0.5 * (1 + erf(x/sqrt(2)))
  float2 gl;
  gl.x = 0.5f * acc0 * (1.f + erff(acc0 * 0.70710678118654752f));
  gl.y = 0.5f * acc1 * (1.f + erff(acc1 * 0.70710678118654752f));
  *(float2*)&out[(size_t)n * HD + 2 * lane] = gl;
}

extern "C" void kernel_launch(void* const* d_in, const int* in_sizes, int n_in,
                              void* d_out, int out_size, void* d_ws, size_t ws_size,
                              hipStream_t stream) {
  const float* x     = (const float*)d_in[0];
  const int2*  adj   = (const int2*)d_in[1];
  const float* wts   = (const float*)d_in[2];
  const float* W     = (const float*)d_in[3];
  const float* a_src = (const float*)d_in[4];
  const float* a_dst = (const float*)d_in[5];
  float* out = (float*)d_out;

  char* p = (char*)d_ws;
  auto carve = [&](size_t bytes) {
    char* q = p;
    p += (bytes + 255) & ~(size_t)255;
    return (void*)q;
  };
  // total ≈ 41 MB
  unsigned short* hbf = (unsigned short*)carve((size_t)N_NODES * HD * sizeof(unsigned short)); // 12.8 MB
  unsigned short* Wt  = (unsigned short*)carve((size_t)HD * DIN * sizeof(unsigned short));     // 64 KB
  float* ssrc   = (float*)carve((size_t)N_NODES * NH * sizeof(float));      // 0.8 MB
  float* sdst   = (float*)carve((size_t)N_NODES * NH * sizeof(float));      // 0.8 MB
  int2*  slots  = (int2*)carve((size_t)N_NODES * CAP * sizeof(int2));       // 25.6 MB
  int*   cursor = (int*)carve((size_t)N_NODES * sizeof(int));               // 0.2 MB

  wconv_kernel<<<(HD * DIN) / 256, 256, 0, stream>>>(W, Wt);
  zero_kernel<<<(N_NODES + 255) / 256, 256, 0, stream>>>(cursor);
  gemm_kernel<<<(N_NODES + GROWS - 1) / GROWS, 256, 0, stream>>>(x, Wt, a_src, a_dst, hbf, ssrc, sdst);
  scatter_kernel<<<(N_EDGES + 255) / 256, 256, 0, stream>>>(adj, wts, cursor, slots);
  node_kernel<<<N_NODES / 2, 128, 0, stream>>>(cursor, slots, (const float4*)ssrc,
                                               (const float4*)sdst,
                                               (const unsigned int*)hbf, out);
}

// Round 10
// 198.242 us; speedup vs baseline: 2.1288x; 1.2502x over previous
//
#include <hip/hip_runtime.h>
#include <hip/hip_bf16.h>

#define N_NODES 50000
#define N_EDGES 800000
#define DIN 256
#define HD 128   // H*D
#define NH 4
#define CAP 64   // max in-degree bucket capacity (Poisson(16): P(>64) ~ 1e-20)

#define GROWS 64     // rows per GEMM block (4 waves x 16)
#define LDK 264      // LDS k-stride in bf16 elems (528 B: 16B-aligned, bank-even)

#define GEMM_BLOCKS ((N_NODES + GROWS - 1) / GROWS)   // 782
#define SCAT_BLOCKS ((N_EDGES + 255) / 256)           // 3125

typedef __bf16 bf16x8 __attribute__((ext_vector_type(8)));
typedef float  f32x4  __attribute__((ext_vector_type(4)));

static __device__ __forceinline__ unsigned short f2bu(float v) {
  union { __hip_bfloat16 b; unsigned short u; } c;
  c.b = __float2bfloat16(v);
  return c.u;
}

// ---------------- init: W transpose+convert AND cursor zero (one launch) -----
__global__ void init_kernel(const float* __restrict__ W,
                            unsigned short* __restrict__ Wt,
                            int* __restrict__ cursor) {
  int i = blockIdx.x * 256 + threadIdx.x;
  if (i < HD * DIN) {
    int c = i >> 8, k = i & 255;
    Wt[c * 256 + k] = f2bu(W[k * HD + c]);
  }
  if (i < N_NODES) cursor[i] = 0;
}

// ---------------- fused: GEMM blocks + scatter blocks (independent work) -----
// blocks [0, GEMM_BLOCKS): h = x @ W via bf16 MFMA (fp32 accum) + fused dots.
// blocks [GEMM_BLOCKS, GEMM_BLOCKS+SCAT_BLOCKS): edge scatter into dst buckets.
// The scatter path is latency-bound (cursor atomic round-trip) and fills the
// GEMM blocks' memory-stall slots when co-resident on a CU.
__global__ __launch_bounds__(256, 2) void fused_gemm_scatter(
    const float* __restrict__ x,
    const unsigned short* __restrict__ Wt,   // bf16 bits [128][256]
    const float* __restrict__ a_src,
    const float* __restrict__ a_dst,
    unsigned short* __restrict__ hbf,        // bf16 bits [N_NODES][HD]
    float* __restrict__ ssrc,
    float* __restrict__ sdst,
    const int2* __restrict__ adj,
    const float* __restrict__ wts,
    int* __restrict__ cursor,
    int2* __restrict__ slots) {
  __shared__ unsigned short xs[GROWS * LDK];   // 33,792 B (allocated for all blocks)
  const int tid = threadIdx.x;

  if (blockIdx.x >= GEMM_BLOCKS) {
    // ---------------- scatter path (identical numerics to round 9) ----------
    int e = (blockIdx.x - GEMM_BLOCKS) * 256 + tid;
    if (e >= N_EDGES) return;
    int2 sd = adj[e];                      // x = src, y = dst
    if ((unsigned)sd.x >= (unsigned)N_NODES || (unsigned)sd.y >= (unsigned)N_NODES) return;
    float g = fmaxf(wts[e], 1e-6f);
    int pos = atomicAdd(&cursor[sd.y], 1);
    if (pos >= CAP) pos = CAP - 1;         // unreachable for this input; never corrupt
    slots[((size_t)sd.y << 6) + pos] = make_int2(sd.x, __float_as_int(g));
    return;
  }

  // ---------------- GEMM path (identical numerics to round 9) ---------------
  const int row0 = blockIdx.x * GROWS;

  // stage + convert x[row0..row0+63][0..255] -> bf16 LDS
#pragma unroll
  for (int it = 0; it < 16; it++) {
    int i  = it * 256 + tid;     // 4096 float4 slots (64 rows x 64)
    int r  = i >> 6;
    int kq = i & 63;
    int row = row0 + r;
    float4 v = make_float4(0.f, 0.f, 0.f, 0.f);
    if (row < N_NODES) v = *(const float4*)(x + (size_t)row * DIN + 4 * kq);
    ushort4 b;
    b.x = f2bu(v.x); b.y = f2bu(v.y); b.z = f2bu(v.z); b.w = f2bu(v.w);
    *(ushort4*)&xs[r * LDK + 4 * kq] = b;    // ds_write_b64
  }
  __syncthreads();

  const int wid  = tid >> 6;      // wave id -> row stripe
  const int lane = tid & 63;
  const int m    = lane & 15;     // A row within tile / B col within tile
  const int q    = lane >> 4;     // quad

  f32x4 acc[8];
#pragma unroll
  for (int t = 0; t < 8; t++) acc[t] = (f32x4){0.f, 0.f, 0.f, 0.f};

  const unsigned short* xbase = &xs[(wid * 16 + m) * LDK];
#pragma unroll
  for (int s = 0; s < 8; s++) {             // k-step: k = 32s
    bf16x8 afrag = *(const bf16x8*)(xbase + 32 * s + 8 * q);   // A[m][32s+8q+j]
#pragma unroll
    for (int t = 0; t < 8; t++) {           // col tile: cols 16t..16t+15
      bf16x8 bfrag = *(const bf16x8*)(Wt + (size_t)(16 * t + m) * 256 + 32 * s + 8 * q);
      acc[t] = __builtin_amdgcn_mfma_f32_16x16x32_bf16(afrag, bfrag, acc[t], 0, 0, 0);
    }
  }

  // D layout: lane holds rows q*4+r (r=0..3), col m of each tile t.
#pragma unroll
  for (int t = 0; t < 8; t++) {
#pragma unroll
    for (int r = 0; r < 4; r++) {
      int row = row0 + wid * 16 + q * 4 + r;
      if (row < N_NODES) hbf[(size_t)row * HD + 16 * t + m] = f2bu(acc[t][r]);
    }
  }

  // head dots from fp32 accumulators; tile t belongs to head t>>1.
  float as[8], ad[8];
#pragma unroll
  for (int t = 0; t < 8; t++) {
    as[t] = a_src[16 * t + m];
    ad[t] = a_dst[16 * t + m];
  }
#pragma unroll
  for (int r = 0; r < 4; r++) {
    float ps[NH] = {0.f, 0.f, 0.f, 0.f};
    float pd[NH] = {0.f, 0.f, 0.f, 0.f};
#pragma unroll
    for (int t = 0; t < 8; t++) {
      ps[t >> 1] = fmaf(acc[t][r], as[t], ps[t >> 1]);
      pd[t >> 1] = fmaf(acc[t][r], ad[t], pd[t >> 1]);
    }
#pragma unroll
    for (int mm = 8; mm >= 1; mm >>= 1) {   // reduce across the 16 lanes of quad q
#pragma unroll
      for (int hh = 0; hh < NH; hh++) {
        ps[hh] += __shfl_xor(ps[hh], mm, 64);
        pd[hh] += __shfl_xor(pd[hh], mm, 64);
      }
    }
    int row = row0 + wid * 16 + q * 4 + r;
    if (m == 0 && row < N_NODES) {
#pragma unroll
      for (int hh = 0; hh < NH; hh++) {
        ssrc[row * NH + hh] = ps[hh];
        sdst[row * NH + hh] = pd[hh];
      }
    }
  }
}

// ---------------- per-node: scores + softmax + aggregate + GELU --------------
// 128 threads = 2 waves; wave w handles node 2*blockIdx.x + w.
// Lane l covers cols {2l, 2l+1}: one packed bf16-pair (4 B) load per gather.
__global__ void node_kernel(const int* __restrict__ cursor,
                            const int2* __restrict__ slots,
                            const float4* __restrict__ ssrc4,
                            const float4* __restrict__ sdst4,
                            const unsigned int* __restrict__ hbf32, // bf16 pairs
                            float* __restrict__ out) {
  const int tid  = threadIdx.x;
  const int wid  = tid >> 6;           // 0/1: which node
  const int lane = tid & 63;
  const int n    = blockIdx.x * 2 + wid;
  const int hh   = lane >> 4;          // head of cols 2l,2l+1

  int deg = cursor[n];
  if (deg > CAP) deg = CAP;

  __shared__ float  sden[2][NH];
  __shared__ int    sidx[2][CAP];
  __shared__ float4 swv[2][CAP];
  if (lane < NH) sden[wid][lane] = 0.f;
  __syncthreads();

  if (lane < deg) {
    int2 sl = slots[((size_t)n << 6) + lane];
    int s = sl.x;
    float g = __int_as_float(sl.y);
    float4 ss = ssrc4[s];        // 0.8 MB buffer: L2-resident gather
    float4 sd = sdst4[n];
    float4 ex;
    ex.x = g * expf(tanhf(ss.x + sd.x));
    ex.y = g * expf(tanhf(ss.y + sd.y));
    ex.z = g * expf(tanhf(ss.z + sd.z));
    ex.w = g * expf(tanhf(ss.w + sd.w));
    sidx[wid][lane] = s;
    swv[wid][lane] = make_float4(ex.x * g, ex.y * g, ex.z * g, ex.w * g);
    atomicAdd(&sden[wid][0], ex.x);
    atomicAdd(&sden[wid][1], ex.y);
    atomicAdd(&sden[wid][2], ex.z);
    atomicAdd(&sden[wid][3], ex.w);
  }
  __syncthreads();

  float dn  = sden[wid][hh];
  float inv = (dn > 0.f) ? 1.f / dn : 0.f;

  float acc0 = 0.f, acc1 = 0.f;
  for (int j = 0; j < deg; j++) {
    float wj = ((const float*)&swv[wid][j])[hh];            // LDS broadcast
    unsigned int u = hbf32[(size_t)sidx[wid][j] * (HD / 2) + lane];
    acc0 = fmaf(wj, __uint_as_float(u << 16), acc0);        // col 2l
    acc1 = fmaf(wj, __uint_as_float(u & 0xffff0000u), acc1);// col 2l+1
  }
  acc0 *= inv;
  acc1 *= inv;

  // exact GELU: x * 0.5 * (1 + erf(x/sqrt(2)))
  float2 gl;
  gl.x = 0.5f * acc0 * (1.f + erff(acc0 * 0.70710678118654752f));
  gl.y = 0.5f * acc1 * (1.f + erff(acc1 * 0.70710678118654752f));
  *(float2*)&out[(size_t)n * HD + 2 * lane] = gl;
}

extern "C" void kernel_launch(void* const* d_in, const int* in_sizes, int n_in,
                              void* d_out, int out_size, void* d_ws, size_t ws_size,
                              hipStream_t stream) {
  const float* x     = (const float*)d_in[0];
  const int2*  adj   = (const int2*)d_in[1];
  const float* wts   = (const float*)d_in[2];
  const float* W     = (const float*)d_in[3];
  const float* a_src = (const float*)d_in[4];
  const float* a_dst = (const float*)d_in[5];
  float* out = (float*)d_out;

  char* p = (char*)d_ws;
  auto carve = [&](size_t bytes) {
    char* q = p;
    p += (bytes + 255) & ~(size_t)255;
    return (void*)q;
  };
  // total ≈ 41 MB
  unsigned short* hbf = (unsigned short*)carve((size_t)N_NODES * HD * sizeof(unsigned short)); // 12.8 MB
  unsigned short* Wt  = (unsigned short*)carve((size_t)HD * DIN * sizeof(unsigned short));     // 64 KB
  float* ssrc   = (float*)carve((size_t)N_NODES * NH * sizeof(float));      // 0.8 MB
  float* sdst   = (float*)carve((size_t)N_NODES * NH * sizeof(float));      // 0.8 MB
  int2*  slots  = (int2*)carve((size_t)N_NODES * CAP * sizeof(int2));       // 25.6 MB
  int*   cursor = (int*)carve((size_t)N_NODES * sizeof(int));               // 0.2 MB

  init_kernel<<<(N_NODES + 255) / 256, 256, 0, stream>>>(W, Wt, cursor);
  fused_gemm_scatter<<<GEMM_BLOCKS + SCAT_BLOCKS, 256, 0, stream>>>(
      x, Wt, a_src, a_dst, hbf, ssrc, sdst, adj, wts, cursor, slots);
  node_kernel<<<N_NODES / 2, 128, 0, stream>>>(cursor, slots, (const float4*)ssrc,
                                               (const float4*)sdst,
                                               (const unsigned int*)hbf, out);
}